// Round 11
// baseline (197.291 us; speedup 1.0000x reference)
//
#include <hip/hip_runtime.h>
#include <hip/hip_bf16.h>

#define N_S     64
#define C_CH    128
#define L_SEQ   1600
#define H_HEADS 8
#define HD      16
#define SEGN    32    // segments per (n,h)
#define SEGL    50    // elements per segment (32*50 = 1600)
#define PADW    136   // weight LDS row pad (bf16 elems)
#define PADT    70    // x/y tile LDS row pad (bf16 elems; 35 dwords -> odd -> conflict-free staging)
#define NHQ     12800 // dwords per (n,h) slab: 25 * 512

typedef __attribute__((ext_vector_type(8))) short bf16x8;
typedef __attribute__((ext_vector_type(4))) float f32x4;

__device__ inline unsigned short f2bf(float f) {
  return __builtin_bit_cast(unsigned short, __float2bfloat16(f));
}
__device__ inline float bflo(unsigned int u) { return __builtin_bit_cast(float, u << 16); }
__device__ inline float bfhi(unsigned int u) { return __builtin_bit_cast(float, u & 0xffff0000u); }
__device__ inline unsigned int pk(float a, float b) {
  return (unsigned int)f2bf(a) | ((unsigned int)f2bf(b) << 16);
}

// x + row_ror<C>(x): DPP row (16 lanes) rotate-add; 4 steps = full 16-lane sum.
template <int CTRL>
__device__ inline float dppadd(float x) {
  int r = __builtin_amdgcn_update_dpp(0, __builtin_bit_cast(int, x), CTRL, 0xF, 0xF, true);
  return x + __builtin_bit_cast(float, r);
}

// Interleaved slab layout: element (nh, l, d) with seg=l/50, j=l%50, ii=j>>1, p=j&1
// lives in dword  nh*NHQ + ii*512 + seg*16 + d   (p: lo/hi bf16 half).

// ---------------- K1: w3 = conv(x, Wa) + ba   (bf16 MFMA, interleaved store) ----------------
__global__ __launch_bounds__(256) void k_gemm1(const float* __restrict__ x,
                                               const float* __restrict__ Wa,
                                               const float* __restrict__ ba,
                                               unsigned int* __restrict__ w3) {
  __shared__ unsigned short was[128 * PADW];   // [o][c] rows
  __shared__ unsigned short xs[128 * PADT];    // [c][l] natural layout
  const int n = blockIdx.y;
  const int l0 = blockIdx.x * 64;
  const int t = threadIdx.x;
  const float* xn = x + (size_t)n * (C_CH * L_SEQ);

#pragma unroll
  for (int it = 0; it < 16; ++it) {
    int pos = it * 256 + t;
    int o = pos >> 5;
    int c4 = (pos & 31) << 2;
    float4 v = *reinterpret_cast<const float4*>(Wa + o * C_CH + c4);
    ushort4 u;
    u.x = f2bf(v.x); u.y = f2bf(v.y); u.z = f2bf(v.z); u.w = f2bf(v.w);
    *reinterpret_cast<ushort4*>(&was[o * PADW + c4]) = u;
  }
#pragma unroll
  for (int it = 0; it < 8; ++it) {
    int pos = it * 256 + t;
    int c = pos >> 4;
    int l4 = (pos & 15) << 2;
    float4 v = *reinterpret_cast<const float4*>(xn + (size_t)c * L_SEQ + l0 + l4);
    ushort4 u;
    u.x = f2bf(v.x); u.y = f2bf(v.y); u.z = f2bf(v.z); u.w = f2bf(v.w);
    *reinterpret_cast<ushort4*>(&xs[c * PADT + l4]) = u;
  }
  __syncthreads();

  const int wv = t >> 6;
  const int lane = t & 63;
  const int r16 = lane & 15;
  const int kg = lane >> 4;
  f32x4 acc[8];
#pragma unroll
  for (int ot = 0; ot < 8; ++ot) acc[ot] = (f32x4){0.f, 0.f, 0.f, 0.f};

#pragma unroll
  for (int ks = 0; ks < 4; ++ks) {
    bf16x8 a;
#pragma unroll
    for (int j = 0; j < 8; ++j)
      a[j] = (short)xs[(ks * 32 + kg * 8 + j) * PADT + wv * 16 + r16];
#pragma unroll
    for (int ot = 0; ot < 8; ++ot) {
      bf16x8 b = *reinterpret_cast<const bf16x8*>(&was[(ot * 16 + r16) * PADW + ks * 32 + kg * 8]);
      acc[ot] = __builtin_amdgcn_mfma_f32_16x16x32_bf16(a, b, acc[ot], 0, 0, 0);
    }
  }
  // D[row=l-local][col=d]; lane holds 4 consecutive l (aligned) at fixed d -> 2 packed dwords
  const int lbase = l0 + wv * 16 + kg * 4;
  const unsigned int lp0 = (unsigned int)lbase >> 1;
  const unsigned int seg0 = lp0 / 25u;
  const unsigned int ii0 = lp0 - seg0 * 25u;
  const unsigned int seg1 = (ii0 == 24u) ? seg0 + 1u : seg0;
  const unsigned int ii1 = (ii0 == 24u) ? 0u : ii0 + 1u;
  const unsigned int off0 = ii0 * 512u + seg0 * 16u + (unsigned int)r16;
  const unsigned int off1 = ii1 * 512u + seg1 * 16u + (unsigned int)r16;
  unsigned int* w3n = w3 + (size_t)(n * H_HEADS) * NHQ;
#pragma unroll
  for (int ot = 0; ot < 8; ++ot) {
    float bav = ba[ot * 16 + r16];
    unsigned int* p = w3n + (size_t)ot * NHQ;
    p[off0] = pk(acc[ot][0] + bav, acc[ot][1] + bav);
    p[off1] = pk(acc[ot][2] + bav, acc[ot][3] + bav);
  }
}

// ---------------- K2: per-(n,h) scan; fully-coalesced interleaved I/O + DPP + register e ----------------
__global__ __launch_bounds__(512, 8) void k_scan(const unsigned int* __restrict__ w3,
                                                 unsigned int* __restrict__ y3,
                                                 const float* __restrict__ temp,
                                                 const float* __restrict__ dbias) {
  __shared__ float stot[SEGN][17];        // per-seg totals; col 16 = pi column
  __shared__ float red[8];

  const int nh = blockIdx.x;
  const int h = nh & 7;
  const int t = threadIdx.x;
  const int d = t & 15;
  const int lane = t & 63;
  const int wv = t >> 6;                  // 0..7
  const int seg = t >> 4;                 // 0..31
  const float tscale = temp[h];
  const float db16 = 16.f * dbias[h];
  // Sigma_d wsq/denom in (0,16], ==16 at l=0 -> exact-at-l0 upper bound on tmp.
  const float M = fmaxf((16.f + db16) * tscale, db16 * tscale);

  // ---- load 25 packed dwords, perfectly coalesced: dword ii*512 + t ----
  unsigned int vp[25];
  const unsigned int* srcd = w3 + (size_t)nh * NHQ;
#pragma unroll
  for (int ii = 0; ii < 25; ++ii) vp[ii] = srcd[ii * 512 + t];

  // ---- sweep 1a: per-segment sum of w^2 per channel ----
  float tot = 0.f;
#pragma unroll
  for (int ii = 0; ii < 25; ++ii) {
    float a = bflo(vp[ii]), b = bfhi(vp[ii]);
    tot += a * a + b * b;
  }
  stot[seg][d] = tot;
  __syncthreads();                        // B1
  // parallel prefix: wave w scans cols w and w+8 over 32 segments (lanes 0..31)
#pragma unroll
  for (int it = 0; it < 2; ++it) {
    int col = wv + it * 8;
    float val = (lane < 32) ? stot[lane][col] : 0.f;
#pragma unroll
    for (int sh = 1; sh < 32; sh <<= 1) {
      float nv = __shfl_up(val, sh);
      if (lane >= sh) val += nv;
    }
    if (lane < 32) stot[lane][col] = val;
  }
  __syncthreads();                        // B2
  const float off = stot[seg][d] - tot;   // exclusive prefix

  // ---- sweep 1b: cumsum -> wsq/denom; DPP 16-lane row-sum; fused exp + 2a totals ----
  unsigned int ep[25];
  float run = off;
  float sAcc = 0.f, wpAcc = 0.f;
  float eprev = 0.f;
#pragma unroll
  for (int i = 0; i < SEGL; ++i) {
    float v = (i & 1) ? bfhi(vp[i >> 1]) : bflo(vp[i >> 1]);
    float wsq = v * v;
    run += wsq;
    float c = __fdividef(wsq, fmaxf(run, 1e-12f));
    c = dppadd<0x128>(c);                 // row_ror:8
    c = dppadd<0x124>(c);                 // row_ror:4
    c = dppadd<0x122>(c);                 // row_ror:2
    c = dppadd<0x121>(c);                 // row_ror:1 -> full 16-lane sum
    float e = __expf((c + db16) * tscale - M);
    sAcc += e;
    wpAcc = fmaf(wsq, e, wpAcc);
    if (i & 1) ep[i >> 1] = pk(eprev, e); else eprev = e;
  }
  // block-reduce S (each lane's sAcc counts its row's e once per d -> /16 at the end)
  {
    float s = sAcc;
#pragma unroll
    for (int mask = 32; mask; mask >>= 1) s += __shfl_xor(s, mask);
    if (lane == 0) red[wv] = s;
  }
  __syncthreads();                        // B3
  float S16 = 0.f;
#pragma unroll
  for (int i2 = 0; i2 < 8; ++i2) S16 += red[i2];
  const float S = S16 * 0.0625f;
  const float ninvS = -1.0f / S;
  const float epsS = 1e-8f * S;

  // ---- sweep 2 prefix: per-seg wp (per d) and pi totals ----
  stot[seg][d] = wpAcc;
  if (d == 0) stot[seg][16] = sAcc;
  __syncthreads();                        // B4
#pragma unroll
  for (int it = 0; it < 2; ++it) {
    int col = wv + it * 8;
    float val = (lane < 32) ? stot[lane][col] : 0.f;
#pragma unroll
    for (int sh = 1; sh < 32; sh <<= 1) {
      float nv = __shfl_up(val, sh);
      if (lane >= sh) val += nv;
    }
    if (lane < 32) stot[lane][col] = val;
  }
  if (wv == 0) {
    float val = (lane < 32) ? stot[lane][16] : 0.f;
#pragma unroll
    for (int sh = 1; sh < 32; sh <<= 1) {
      float nv = __shfl_up(val, sh);
      if (lane >= sh) val += nv;
    }
    if (lane < 32) stot[lane][16] = val;
  }
  __syncthreads();                        // B5
  const float wp_off = stot[seg][d] - wpAcc;
  const float pi_off = stot[seg][16] - sAcc;

  // ---- sweep 2b: unnormalized running cumsums -> y in place of vp ----
  {
    float run_wp = wp_off, run_pi = pi_off;
    float ylo = 0.f;
#pragma unroll
    for (int i = 0; i < SEGL; ++i) {
      float v = (i & 1) ? bfhi(vp[i >> 1]) : bflo(vp[i >> 1]);
      float e = (i & 1) ? bfhi(ep[i >> 1]) : bflo(ep[i >> 1]);
      run_pi += e;
      run_wp = fmaf(v * v, e, run_wp);
      float dn = run_pi + epsS;
      float y = (v * e) * __fdividef(dn, dn + run_wp) * ninvS;
      if (i & 1) vp[i >> 1] = pk(ylo, y); else ylo = y;
    }
  }
  // ---- store, perfectly coalesced ----
  unsigned int* dstd = y3 + (size_t)nh * NHQ;
#pragma unroll
  for (int ii = 0; ii < 25; ++ii) dstd[ii * 512 + t] = vp[ii];
}

// ---------------- K3: out = relu(Wp . y + bp + x)  (bf16 MFMA, interleaved y3 read) ----------------
__global__ __launch_bounds__(256) void k_gemm2(const unsigned int* __restrict__ y3,
                                               const float* __restrict__ Wp,
                                               const float* __restrict__ bp,
                                               const float* __restrict__ x,
                                               float* __restrict__ out) {
  __shared__ unsigned short wps[128 * PADW];   // [o][c] rows
  __shared__ unsigned short ys[128 * PADT];    // [c][l] natural layout
  const int n = blockIdx.y;
  const int l0 = blockIdx.x * 64;
  const int t = threadIdx.x;

#pragma unroll
  for (int it = 0; it < 16; ++it) {
    int pos = it * 256 + t;
    int o = pos >> 5;
    int c4 = (pos & 31) << 2;
    float4 v = *reinterpret_cast<const float4*>(Wp + o * C_CH + c4);
    ushort4 u;
    u.x = f2bf(v.x); u.y = f2bf(v.y); u.z = f2bf(v.z); u.w = f2bf(v.w);
    *reinterpret_cast<ushort4*>(&wps[o * PADW + c4]) = u;
  }
  // stage y tile: 16 dword reads/thread from interleaved slabs -> ys[c][l]
  const int lpb = l0 >> 1;
#pragma unroll
  for (int k = 0; k < 16; ++k) {
    int e = k * 256 + t;                 // 0..4095
    int lpl = e >> 7;                    // 0..31
    int hd = e & 127;                    // c = 16h+d
    unsigned int lp = (unsigned int)(lpb + lpl);
    unsigned int sg = lp / 25u;
    unsigned int ii = lp - sg * 25u;
    unsigned int vdw = y3[(size_t)(n * H_HEADS + (hd >> 4)) * NHQ + ii * 512u + sg * 16u + (hd & 15)];
    *reinterpret_cast<unsigned int*>(&ys[hd * PADT + 2 * lpl]) = vdw;
  }
  __syncthreads();

  const int wv = t >> 6;
  const int lane = t & 63;
  const int r16 = lane & 15;
  const int kg = lane >> 4;
  f32x4 acc[8];
#pragma unroll
  for (int ot = 0; ot < 8; ++ot) acc[ot] = (f32x4){0.f, 0.f, 0.f, 0.f};

#pragma unroll
  for (int ks = 0; ks < 4; ++ks) {
    bf16x8 b;
#pragma unroll
    for (int j = 0; j < 8; ++j)
      b[j] = (short)ys[(ks * 32 + kg * 8 + j) * PADT + wv * 16 + r16];
#pragma unroll
    for (int ot = 0; ot < 8; ++ot) {
      bf16x8 a = *reinterpret_cast<const bf16x8*>(&wps[(ot * 16 + r16) * PADW + ks * 32 + kg * 8]);
      acc[ot] = __builtin_amdgcn_mfma_f32_16x16x32_bf16(a, b, acc[ot], 0, 0, 0);
    }
  }
  const int gl = l0 + wv * 16 + r16;
#pragma unroll
  for (int ot = 0; ot < 8; ++ot) {
#pragma unroll
    for (int i = 0; i < 4; ++i) {
      int o = ot * 16 + kg * 4 + i;
      size_t idx = (size_t)n * (C_CH * L_SEQ) + (size_t)o * L_SEQ + gl;
      float r = acc[ot][i] + bp[o] + x[idx];
      out[idx] = fmaxf(r, 0.f);
    }
  }
}

extern "C" void kernel_launch(void* const* d_in, const int* in_sizes, int n_in,
                              void* d_out, int out_size, void* d_ws, size_t ws_size,
                              hipStream_t stream) {
  const float* x     = (const float*)d_in[0];
  const float* Wa    = (const float*)d_in[1];
  const float* ba    = (const float*)d_in[2];
  const float* Wp    = (const float*)d_in[3];
  const float* bp    = (const float*)d_in[4];
  const float* temp  = (const float*)d_in[5];
  const float* dbias = (const float*)d_in[6];
  float* out = (float*)d_out;

  unsigned int* w3 = (unsigned int*)d_ws;                           // 26.2 MB
  unsigned int* y3 = w3 + (size_t)N_S * H_HEADS * NHQ;              // 26.2 MB

  k_gemm1<<<dim3(L_SEQ / 64, N_S), 256, 0, stream>>>(x, Wa, ba, w3);
  k_scan<<<N_S * H_HEADS, 512, 0, stream>>>(w3, y3, temp, dbias);
  k_gemm2<<<dim3(L_SEQ / 64, N_S), 256, 0, stream>>>(y3, Wp, bp, x, out);
}

// Round 12
// 74.463 us; speedup vs baseline: 2.6495x; 2.6495x over previous
//
#include <hip/hip_runtime.h>
#include <hip/hip_bf16.h>

#define N_S     64
#define C_CH    128
#define L_SEQ   1600
#define H_HEADS 8
#define HD      16
#define SEGN    32    // segments per (n,h)
#define SEGL    50    // elements per segment (32*50 = 1600)
#define PADW    136   // weight LDS row pad (bf16 elems)
#define PADT    70    // x/y tile LDS row pad (bf16 elems; 35 dwords -> odd -> conflict-free staging)
#define NHQ     12800 // dwords per (n,h) slab: 25 * 512

typedef __attribute__((ext_vector_type(8))) short bf16x8;
typedef __attribute__((ext_vector_type(4))) float f32x4;

__device__ inline unsigned short f2bf(float f) {
  return __builtin_bit_cast(unsigned short, __float2bfloat16(f));
}
__device__ inline float bflo(unsigned int u) { return __builtin_bit_cast(float, u << 16); }
__device__ inline float bfhi(unsigned int u) { return __builtin_bit_cast(float, u & 0xffff0000u); }
__device__ inline unsigned int pk(float a, float b) {
  return (unsigned int)f2bf(a) | ((unsigned int)f2bf(b) << 16);
}

// x + row_ror<C>(x): DPP row (16 lanes) rotate-add; 4 steps = full 16-lane sum.
template <int CTRL>
__device__ inline float dppadd(float x) {
  int r = __builtin_amdgcn_update_dpp(0, __builtin_bit_cast(int, x), CTRL, 0xF, 0xF, true);
  return x + __builtin_bit_cast(float, r);
}

// Interleaved slab layout: element (nh, l, d) with seg=l/50, j=l%50, ii=j>>1, p=j&1
// lives in dword  nh*NHQ + ii*512 + seg*16 + d   (p: lo/hi bf16 half).

// ---------------- K1: w3 = conv(x, Wa) + ba   (bf16 MFMA, interleaved store) ----------------
__global__ __launch_bounds__(256) void k_gemm1(const float* __restrict__ x,
                                               const float* __restrict__ Wa,
                                               const float* __restrict__ ba,
                                               unsigned int* __restrict__ w3) {
  __shared__ unsigned short was[128 * PADW];   // [o][c] rows
  __shared__ unsigned short xs[128 * PADT];    // [c][l] natural layout
  const int n = blockIdx.y;
  const int l0 = blockIdx.x * 64;
  const int t = threadIdx.x;
  const float* xn = x + (size_t)n * (C_CH * L_SEQ);

#pragma unroll
  for (int it = 0; it < 16; ++it) {
    int pos = it * 256 + t;
    int o = pos >> 5;
    int c4 = (pos & 31) << 2;
    float4 v = *reinterpret_cast<const float4*>(Wa + o * C_CH + c4);
    ushort4 u;
    u.x = f2bf(v.x); u.y = f2bf(v.y); u.z = f2bf(v.z); u.w = f2bf(v.w);
    *reinterpret_cast<ushort4*>(&was[o * PADW + c4]) = u;
  }
#pragma unroll
  for (int it = 0; it < 8; ++it) {
    int pos = it * 256 + t;
    int c = pos >> 4;
    int l4 = (pos & 15) << 2;
    float4 v = *reinterpret_cast<const float4*>(xn + (size_t)c * L_SEQ + l0 + l4);
    ushort4 u;
    u.x = f2bf(v.x); u.y = f2bf(v.y); u.z = f2bf(v.z); u.w = f2bf(v.w);
    *reinterpret_cast<ushort4*>(&xs[c * PADT + l4]) = u;
  }
  __syncthreads();

  const int wv = t >> 6;
  const int lane = t & 63;
  const int r16 = lane & 15;
  const int kg = lane >> 4;
  f32x4 acc[8];
#pragma unroll
  for (int ot = 0; ot < 8; ++ot) acc[ot] = (f32x4){0.f, 0.f, 0.f, 0.f};

#pragma unroll
  for (int ks = 0; ks < 4; ++ks) {
    bf16x8 a;
#pragma unroll
    for (int j = 0; j < 8; ++j)
      a[j] = (short)xs[(ks * 32 + kg * 8 + j) * PADT + wv * 16 + r16];
#pragma unroll
    for (int ot = 0; ot < 8; ++ot) {
      bf16x8 b = *reinterpret_cast<const bf16x8*>(&was[(ot * 16 + r16) * PADW + ks * 32 + kg * 8]);
      acc[ot] = __builtin_amdgcn_mfma_f32_16x16x32_bf16(a, b, acc[ot], 0, 0, 0);
    }
  }
  // D[row=l-local][col=d]; lane holds 4 consecutive l (aligned) at fixed d -> 2 packed dwords
  const int lbase = l0 + wv * 16 + kg * 4;
  const unsigned int lp0 = (unsigned int)lbase >> 1;
  const unsigned int seg0 = lp0 / 25u;
  const unsigned int ii0 = lp0 - seg0 * 25u;
  const unsigned int seg1 = (ii0 == 24u) ? seg0 + 1u : seg0;
  const unsigned int ii1 = (ii0 == 24u) ? 0u : ii0 + 1u;
  const unsigned int off0 = ii0 * 512u + seg0 * 16u + (unsigned int)r16;
  const unsigned int off1 = ii1 * 512u + seg1 * 16u + (unsigned int)r16;
  unsigned int* w3n = w3 + (size_t)(n * H_HEADS) * NHQ;
#pragma unroll
  for (int ot = 0; ot < 8; ++ot) {
    float bav = ba[ot * 16 + r16];
    unsigned int* p = w3n + (size_t)ot * NHQ;
    p[off0] = pk(acc[ot][0] + bav, acc[ot][1] + bav);
    p[off1] = pk(acc[ot][2] + bav, acc[ot][3] + bav);
  }
}

// ---------------- K2: per-(n,h) scan; fully-coalesced interleaved I/O + DPP + register e ----------------
__global__ __launch_bounds__(512) void k_scan(const unsigned int* __restrict__ w3,
                                              unsigned int* __restrict__ y3,
                                              const float* __restrict__ temp,
                                              const float* __restrict__ dbias) {
  __shared__ float stot[SEGN][17];        // per-seg totals; col 16 = pi column
  __shared__ float red[8];

  const int nh = blockIdx.x;
  const int h = nh & 7;
  const int t = threadIdx.x;
  const int d = t & 15;
  const int lane = t & 63;
  const int wv = t >> 6;                  // 0..7
  const int seg = t >> 4;                 // 0..31
  const float tscale = temp[h];
  const float db16 = 16.f * dbias[h];
  // Sigma_d wsq/denom in (0,16], ==16 at l=0 -> exact-at-l0 upper bound on tmp.
  const float M = fmaxf((16.f + db16) * tscale, db16 * tscale);

  // ---- load 25 packed dwords, perfectly coalesced: dword ii*512 + t ----
  unsigned int vp[25];
  const unsigned int* srcd = w3 + (size_t)nh * NHQ;
#pragma unroll
  for (int ii = 0; ii < 25; ++ii) vp[ii] = srcd[ii * 512 + t];

  // ---- sweep 1a: per-segment sum of w^2 per channel ----
  float tot = 0.f;
#pragma unroll
  for (int ii = 0; ii < 25; ++ii) {
    float a = bflo(vp[ii]), b = bfhi(vp[ii]);
    tot += a * a + b * b;
  }
  stot[seg][d] = tot;
  __syncthreads();                        // B1
  // parallel prefix: wave w scans cols w and w+8 over 32 segments (lanes 0..31)
#pragma unroll
  for (int it = 0; it < 2; ++it) {
    int col = wv + it * 8;
    float val = (lane < 32) ? stot[lane][col] : 0.f;
#pragma unroll
    for (int sh = 1; sh < 32; sh <<= 1) {
      float nv = __shfl_up(val, sh);
      if (lane >= sh) val += nv;
    }
    if (lane < 32) stot[lane][col] = val;
  }
  __syncthreads();                        // B2
  const float off = stot[seg][d] - tot;   // exclusive prefix

  // ---- sweep 1b: cumsum -> wsq/denom; DPP 16-lane row-sum; fused exp + 2a totals ----
  unsigned int ep[25];
  float run = off;
  float sAcc = 0.f, wpAcc = 0.f;
  float eprev = 0.f;
#pragma unroll
  for (int i = 0; i < SEGL; ++i) {
    float v = (i & 1) ? bfhi(vp[i >> 1]) : bflo(vp[i >> 1]);
    float wsq = v * v;
    run += wsq;
    float c = __fdividef(wsq, fmaxf(run, 1e-12f));
    c = dppadd<0x128>(c);                 // row_ror:8
    c = dppadd<0x124>(c);                 // row_ror:4
    c = dppadd<0x122>(c);                 // row_ror:2
    c = dppadd<0x121>(c);                 // row_ror:1 -> full 16-lane sum
    float e = __expf((c + db16) * tscale - M);
    sAcc += e;
    wpAcc = fmaf(wsq, e, wpAcc);
    if (i & 1) ep[i >> 1] = pk(eprev, e); else eprev = e;
  }
  // block-reduce S (each lane's sAcc counts its row's e once per d -> /16 at the end)
  {
    float s = sAcc;
#pragma unroll
    for (int mask = 32; mask; mask >>= 1) s += __shfl_xor(s, mask);
    if (lane == 0) red[wv] = s;
  }
  __syncthreads();                        // B3
  float S16 = 0.f;
#pragma unroll
  for (int i2 = 0; i2 < 8; ++i2) S16 += red[i2];
  const float S = S16 * 0.0625f;
  const float ninvS = -1.0f / S;
  const float epsS = 1e-8f * S;

  // ---- sweep 2 prefix: per-seg wp (per d) and pi totals ----
  stot[seg][d] = wpAcc;
  if (d == 0) stot[seg][16] = sAcc;
  __syncthreads();                        // B4
#pragma unroll
  for (int it = 0; it < 2; ++it) {
    int col = wv + it * 8;
    float val = (lane < 32) ? stot[lane][col] : 0.f;
#pragma unroll
    for (int sh = 1; sh < 32; sh <<= 1) {
      float nv = __shfl_up(val, sh);
      if (lane >= sh) val += nv;
    }
    if (lane < 32) stot[lane][col] = val;
  }
  if (wv == 0) {
    float val = (lane < 32) ? stot[lane][16] : 0.f;
#pragma unroll
    for (int sh = 1; sh < 32; sh <<= 1) {
      float nv = __shfl_up(val, sh);
      if (lane >= sh) val += nv;
    }
    if (lane < 32) stot[lane][16] = val;
  }
  __syncthreads();                        // B5
  const float wp_off = stot[seg][d] - wpAcc;
  const float pi_off = stot[seg][16] - sAcc;

  // ---- sweep 2b: unnormalized running cumsums -> y in place of vp ----
  {
    float run_wp = wp_off, run_pi = pi_off;
    float ylo = 0.f;
#pragma unroll
    for (int i = 0; i < SEGL; ++i) {
      float v = (i & 1) ? bfhi(vp[i >> 1]) : bflo(vp[i >> 1]);
      float e = (i & 1) ? bfhi(ep[i >> 1]) : bflo(ep[i >> 1]);
      run_pi += e;
      run_wp = fmaf(v * v, e, run_wp);
      float dn = run_pi + epsS;
      float y = (v * e) * __fdividef(dn, dn + run_wp) * ninvS;
      if (i & 1) vp[i >> 1] = pk(ylo, y); else ylo = y;
    }
  }
  // ---- store, perfectly coalesced ----
  unsigned int* dstd = y3 + (size_t)nh * NHQ;
#pragma unroll
  for (int ii = 0; ii < 25; ++ii) dstd[ii * 512 + t] = vp[ii];
}

// ---------------- K3: out = relu(Wp . y + bp + x)  (bf16 MFMA, interleaved y3 read) ----------------
__global__ __launch_bounds__(256) void k_gemm2(const unsigned int* __restrict__ y3,
                                               const float* __restrict__ Wp,
                                               const float* __restrict__ bp,
                                               const float* __restrict__ x,
                                               float* __restrict__ out) {
  __shared__ unsigned short wps[128 * PADW];   // [o][c] rows
  __shared__ unsigned short ys[128 * PADT];    // [c][l] natural layout
  const int n = blockIdx.y;
  const int l0 = blockIdx.x * 64;
  const int t = threadIdx.x;

#pragma unroll
  for (int it = 0; it < 16; ++it) {
    int pos = it * 256 + t;
    int o = pos >> 5;
    int c4 = (pos & 31) << 2;
    float4 v = *reinterpret_cast<const float4*>(Wp + o * C_CH + c4);
    ushort4 u;
    u.x = f2bf(v.x); u.y = f2bf(v.y); u.z = f2bf(v.z); u.w = f2bf(v.w);
    *reinterpret_cast<ushort4*>(&wps[o * PADW + c4]) = u;
  }
  // stage y tile: 16 dword reads/thread from interleaved slabs -> ys[c][l]
  const int lpb = l0 >> 1;
#pragma unroll
  for (int k = 0; k < 16; ++k) {
    int e = k * 256 + t;                 // 0..4095
    int lpl = e >> 7;                    // 0..31
    int hd = e & 127;                    // c = 16h+d
    unsigned int lp = (unsigned int)(lpb + lpl);
    unsigned int sg = lp / 25u;
    unsigned int ii = lp - sg * 25u;
    unsigned int vdw = y3[(size_t)(n * H_HEADS + (hd >> 4)) * NHQ + ii * 512u + sg * 16u + (hd & 15)];
    *reinterpret_cast<unsigned int*>(&ys[hd * PADT + 2 * lpl]) = vdw;
  }
  __syncthreads();

  const int wv = t >> 6;
  const int lane = t & 63;
  const int r16 = lane & 15;
  const int kg = lane >> 4;
  f32x4 acc[8];
#pragma unroll
  for (int ot = 0; ot < 8; ++ot) acc[ot] = (f32x4){0.f, 0.f, 0.f, 0.f};

#pragma unroll
  for (int ks = 0; ks < 4; ++ks) {
    bf16x8 b;
#pragma unroll
    for (int j = 0; j < 8; ++j)
      b[j] = (short)ys[(ks * 32 + kg * 8 + j) * PADT + wv * 16 + r16];
#pragma unroll
    for (int ot = 0; ot < 8; ++ot) {
      bf16x8 a = *reinterpret_cast<const bf16x8*>(&wps[(ot * 16 + r16) * PADW + ks * 32 + kg * 8]);
      acc[ot] = __builtin_amdgcn_mfma_f32_16x16x32_bf16(a, b, acc[ot], 0, 0, 0);
    }
  }
  const int gl = l0 + wv * 16 + r16;
#pragma unroll
  for (int ot = 0; ot < 8; ++ot) {
#pragma unroll
    for (int i = 0; i < 4; ++i) {
      int o = ot * 16 + kg * 4 + i;
      size_t idx = (size_t)n * (C_CH * L_SEQ) + (size_t)o * L_SEQ + gl;
      float r = acc[ot][i] + bp[o] + x[idx];
      out[idx] = fmaxf(r, 0.f);
    }
  }
}

extern "C" void kernel_launch(void* const* d_in, const int* in_sizes, int n_in,
                              void* d_out, int out_size, void* d_ws, size_t ws_size,
                              hipStream_t stream) {
  const float* x     = (const float*)d_in[0];
  const float* Wa    = (const float*)d_in[1];
  const float* ba    = (const float*)d_in[2];
  const float* Wp    = (const float*)d_in[3];
  const float* bp    = (const float*)d_in[4];
  const float* temp  = (const float*)d_in[5];
  const float* dbias = (const float*)d_in[6];
  float* out = (float*)d_out;

  unsigned int* w3 = (unsigned int*)d_ws;                           // 26.2 MB
  unsigned int* y3 = w3 + (size_t)N_S * H_HEADS * NHQ;              // 26.2 MB

  k_gemm1<<<dim3(L_SEQ / 64, N_S), 256, 0, stream>>>(x, Wa, ba, w3);
  k_scan<<<N_S * H_HEADS, 512, 0, stream>>>(w3, y3, temp, dbias);
  k_gemm2<<<dim3(L_SEQ / 64, N_S), 256, 0, stream>>>(y3, Wp, bp, x, out);
}